// Round 5
// baseline (295.938 us; speedup 1.0000x reference)
//
#include <hip/hip_runtime.h>

// PillarMaxPooling: Linear(10->64,nobias) -> BN1d(eval,eps=1e-3) -> ReLU ->
// segment_max -> clamp0.
//
// R8 (262us): 4-kernel counting sort + pool(83us).
// R9 (370us, REVERTED): 128-token gather window -> FETCH +76MB.
// R10 (283us, REVERTED): persistent pool blocks -> FETCH+WRITE +85MB.
// R11 (216us): one-pass fixed-capacity (bucket,region) token scatter + R8
//   pool. Pool 82us: FETCH 155MB = 2M x 77B random gather, serial chain.
// R12 (CONTAINER DIED x2): payload scatter needed 77MB workspace, shrink
//   floor 48MB; only ~13MB ever proven. Prime suspect: OOB workspace write.
// R13: same payload idea, workspace-safe. Host picks per ws_size:
//   PAY path (needs ~72MB): scatter reads gf densely (lane-stride 40B),
//     pkrtz-converts, writes 3 u64 SoA planes (plane stride E*CAPR) ->
//     pool is pure streaming (3 coalesced 8B loads/lane, no gather/cvt).
//   TOK path (fits anywhere >= ~13MB): R11 scheme verbatim (proven 216us).
//   Both via template<bool PAY>; overflow -> direct-MLP atomicMax fallback.

#define C_IN   10
#define C_OUT  64
#define BSHIFT 7
#define BPILL  128
#define MAXNBP 2048              // supports M <= ~258k
#define NREG   8
#define SBLK   256
#define SCHUNK 4096
#define PPT    (SCHUNK / SBLK)   // 16 points per thread
#define PBLK   512
#define TRASH  128               // acc row for masked lanes
#define SENT   (128u << 24)

typedef _Float16 half8 __attribute__((ext_vector_type(8)));
typedef float    f32x4 __attribute__((ext_vector_type(4)));
typedef unsigned long long u64;

// Overflow fallback: direct per-point MLP + device atomicMax on out.
// Never taken for the bench distribution; noinline keeps hot loop clean.
__device__ __attribute__((noinline))
void fallback_point(int p, int m, const float* gf, const float* W,
                    const float* gamma, const float* beta,
                    const float* rmean, const float* rvar,
                    float* out, int* ovf) {
    atomicExch(ovf, 1);
    const float* x = gf + (size_t)p * C_IN;
    unsigned* o = (unsigned*)out + (size_t)m * C_OUT;
#pragma clang loop unroll(disable)
    for (int c = 0; c < C_OUT; ++c) {
        float is = gamma[c] * rsqrtf(rvar[c] + 1e-3f);
        float bb = fmaf(-rmean[c], is, beta[c]);
        float d = 0.f;
        for (int k = 0; k < C_IN; ++k) d = fmaf(x[k], W[k * C_OUT + c], d);
        atomicMax(o + c, __float_as_uint(fmaxf(fmaf(d, is, bb), 0.f)));
    }
}

// ---------- K1: one-pass scatter into fixed-capacity (bucket,region) cells --
// phase1: LDS hist, per-point rank from atomic return (held in regs)
// phase2: one global atomicAdd per (block, nonempty bucket) -> cell base
// phase3: PAY: dense gf read + pkrtz + 3 u64 plane stores; TOK: 4B token
template <bool PAY>
__global__ __launch_bounds__(SBLK)
void k_scatter(const int* __restrict__ idx,
               const float* __restrict__ gf,
               const float* __restrict__ W,
               const float* __restrict__ gamma,
               const float* __restrict__ beta,
               const float* __restrict__ rmean,
               const float* __restrict__ rvar,
               int* __restrict__ cnt, int* __restrict__ ovf,
               u64* __restrict__ pay, unsigned* __restrict__ tok,
               float* __restrict__ out,
               int P, int NBpad, int CAPR, size_t PS) {
    __shared__ int lh[MAXNBP];
    __shared__ int rbase[MAXNBP];
    const int t = threadIdx.x;
    const int r = blockIdx.x & (NREG - 1);   // region ~ XCD (round-robin)

    for (int b = t; b < NBpad; b += SBLK) lh[b] = 0;
    __syncthreads();

    const int base = blockIdx.x * SCHUNK;
    int mm[PPT], rk[PPT];
#pragma unroll
    for (int i = 0; i < PPT; ++i) {
        int p = base + i * SBLK + t;
        mm[i] = (p < P) ? idx[p] : -1;
        rk[i] = (mm[i] >= 0) ? atomicAdd(&lh[mm[i] >> BSHIFT], 1) : 0;
    }
    __syncthreads();

    int* crow = cnt + (size_t)r * NBpad;
    for (int b = t; b < NBpad; b += SBLK) {
        int h = lh[b];
        rbase[b] = h ? atomicAdd(&crow[b], h) : 0;
    }
    __syncthreads();

    const float2* gf2 = (const float2*)gf;
#pragma unroll
    for (int i = 0; i < PPT; ++i) {
        if (mm[i] < 0) continue;
        int p = base + i * SBLK + t;
        int b = mm[i] >> BSHIFT;
        int slot = rbase[b] + rk[i];
        if (slot < CAPR) {
            size_t off = ((size_t)b * NREG + r) * CAPR + slot;
            if constexpr (PAY) {
                const float2* src = gf2 + (size_t)p * 5;  // dense: stride 40B
                float2 x0 = src[0], x1 = src[1], x2 = src[2];
                float2 x3 = src[3], x4 = src[4];
                unsigned u0 = __builtin_bit_cast(unsigned, __builtin_amdgcn_cvt_pkrtz(x0.x, x0.y));
                unsigned u1 = __builtin_bit_cast(unsigned, __builtin_amdgcn_cvt_pkrtz(x1.x, x1.y));
                unsigned u2 = __builtin_bit_cast(unsigned, __builtin_amdgcn_cvt_pkrtz(x2.x, x2.y));
                unsigned u3 = __builtin_bit_cast(unsigned, __builtin_amdgcn_cvt_pkrtz(x3.x, x3.y));
                unsigned u4 = __builtin_bit_cast(unsigned, __builtin_amdgcn_cvt_pkrtz(x4.x, x4.y));
                pay[off]          = (u64)u0 | ((u64)u1 << 32);
                pay[off + PS]     = (u64)u2 | ((u64)u3 << 32);
                pay[off + 2 * PS] = (u64)u4 |
                    ((u64)(unsigned)(mm[i] & (BPILL - 1)) << 32);
            } else {
                tok[off] = (unsigned)p | ((unsigned)(mm[i] & (BPILL - 1)) << 24);
            }
        } else {
            fallback_point(p, mm[i], gf, W, gamma, beta, rmean, rvar, out, ovf);
        }
    }
}

// ---------- K2: pool — PAY: streaming planes; TOK: token + gf gather --------
template <bool PAY>
__global__ __launch_bounds__(PBLK, 8)
void k_pool(const float* __restrict__ gf,
            const u64* __restrict__ pay,
            const unsigned* __restrict__ tok,
            const int* __restrict__ cnt,
            const int* __restrict__ ovf,
            const float* __restrict__ W,
            const float* __restrict__ gamma,
            const float* __restrict__ beta,
            const float* __restrict__ rmean,
            const float* __restrict__ rvar,
            float* __restrict__ out, int M, int NBpad, int CAPR, size_t PS) {
    __shared__ unsigned int acc[129 * 65];   // stride 65; row 128 = trash
    const int t = threadIdx.x;
    const int lane = t & 63;
    const int wv = t >> 6;                   // wave == region 0..7
    const int n = lane & 15;
    const int q = lane >> 4;

    for (int i = t; i < 129 * 65; i += PBLK) acc[i] = 0u;

    // B fragments: W rows k>=10 zeroed -> A K-padding free
    half8 bfrag[4];
    float inv[4], bia[4];
#pragma unroll
    for (int tt = 0; tt < 4; ++tt) {
        int c = tt * 16 + n;
#pragma unroll
        for (int j = 0; j < 8; ++j) {
            int k = q * 8 + j;
            bfrag[tt][j] = (k < C_IN) ? (_Float16)W[k * C_OUT + c] : (_Float16)0.f;
        }
        float is = gamma[c] * rsqrtf(rvar[c] + 1e-3f);
        inv[tt] = is;
        bia[tt] = fmaf(-rmean[c], is, beta[c]);
    }
    __syncthreads();

    const int blk = blockIdx.x;
    const int cn = min(cnt[(size_t)wv * NBpad + blk], CAPR);   // real count
    const size_t cbase = ((size_t)blk * NREG + wv) * CAPR;
    const float2* gf2 = (const float2*)gf;

    for (int rb = 0; rb < cn; rb += 64) {
        int slot = rb + lane;
        int u0, u1, u2, u3, u4, ml;
        if constexpr (PAY) {
            // streaming: 3 coalesced 8B plane loads, linear addresses
            u64 w0 = 0, w1 = 0, w2 = ((u64)TRASH) << 32;
            if (slot < cn) {
                w0 = pay[cbase + slot];
                w1 = pay[cbase + slot + PS];
                w2 = pay[cbase + slot + 2 * PS];
            }
            u0 = (int)(unsigned)w0; u1 = (int)(unsigned)(w0 >> 32);
            u2 = (int)(unsigned)w1; u3 = (int)(unsigned)(w1 >> 32);
            u4 = (int)(unsigned)w2; ml = (int)(unsigned)(w2 >> 32);
        } else {
            // token + random 40B gf gather (R11 path)
            unsigned v = (slot < cn) ? tok[cbase + slot] : SENT;
            const float2* src = gf2 + (size_t)(v & 0xFFFFFFu) * 5;
            float2 x0 = src[0], x1 = src[1], x2 = src[2];
            float2 x3 = src[3], x4 = src[4];
            u0 = __builtin_bit_cast(int, __builtin_amdgcn_cvt_pkrtz(x0.x, x0.y));
            u1 = __builtin_bit_cast(int, __builtin_amdgcn_cvt_pkrtz(x1.x, x1.y));
            u2 = __builtin_bit_cast(int, __builtin_amdgcn_cvt_pkrtz(x2.x, x2.y));
            u3 = __builtin_bit_cast(int, __builtin_amdgcn_cvt_pkrtz(x3.x, x3.y));
            u4 = __builtin_bit_cast(int, __builtin_amdgcn_cvt_pkrtz(x4.x, x4.y));
            ml = (int)(v >> 24);
        }

        const int ng = min(4, ((cn - rb) + 15) >> 4);   // 16-groups left
#pragma unroll
        for (int g = 0; g < 4; ++g) {
            if (g >= ng) break;              // wave-uniform
            const int sl = (g << 4) + n;     // source lane: point g*16+n
            int b0 = __shfl(u0, sl, 64);
            int b1 = __shfl(u1, sl, 64);
            int b2 = __shfl(u2, sl, 64);
            int b3 = __shfl(u3, sl, 64);
            int b4 = __shfl(u4, sl, 64);
            int4 a32;
            a32.x = (q == 0) ? b0 : ((q == 1) ? b4 : 0);
            a32.y = (q == 0) ? b1 : 0;
            a32.z = (q == 0) ? b2 : 0;
            a32.w = (q == 0) ? b3 : 0;
            half8 a = __builtin_bit_cast(half8, a32);
            f32x4 z = {0.f, 0.f, 0.f, 0.f};
            f32x4 d0 = __builtin_amdgcn_mfma_f32_16x16x32_f16(a, bfrag[0], z, 0, 0, 0);
            f32x4 d1 = __builtin_amdgcn_mfma_f32_16x16x32_f16(a, bfrag[1], z, 0, 0, 0);
            f32x4 d2 = __builtin_amdgcn_mfma_f32_16x16x32_f16(a, bfrag[2], z, 0, 0, 0);
            f32x4 d3 = __builtin_amdgcn_mfma_f32_16x16x32_f16(a, bfrag[3], z, 0, 0, 0);
#pragma unroll
            for (int r = 0; r < 4; ++r) {    // C row = 4q+r = point
                int mlr = __shfl(ml, (g << 4) + (q << 2) + r, 64);
                int abase = mlr * 65 + n;
                float h0 = fmaxf(fmaf(d0[r], inv[0], bia[0]), 0.f);
                float h1 = fmaxf(fmaf(d1[r], inv[1], bia[1]), 0.f);
                float h2 = fmaxf(fmaf(d2[r], inv[2], bia[2]), 0.f);
                float h3 = fmaxf(fmaf(d3[r], inv[3], bia[3]), 0.f);
                atomicMax(&acc[abase +  0], __float_as_uint(h0));
                atomicMax(&acc[abase + 16], __float_as_uint(h1));
                atomicMax(&acc[abase + 32], __float_as_uint(h2));
                atomicMax(&acc[abase + 48], __float_as_uint(h3));
            }
        }
    }
    __syncthreads();

    // coalesced writeback of 128 pillars x 64 channels; merge if overflow ran
    const int anyovf = ovf[0];
    const int mbase = blk * BPILL;
#pragma unroll
    for (int i = 0; i < (BPILL * C_OUT) / PBLK; ++i) {
        int wdx = i * PBLK + t;
        int row = wdx >> 6, c = wdx & 63;
        int m = mbase + row;
        if (m < M) {
            unsigned uv = acc[row * 65 + c];
            if (anyovf) atomicMax((unsigned*)out + (size_t)m * C_OUT + c, uv);
            else        out[(size_t)m * C_OUT + c] = __uint_as_float(uv);
        }
    }
}

extern "C" void kernel_launch(void* const* d_in, const int* in_sizes, int n_in,
                              void* d_out, int out_size, void* d_ws, size_t ws_size,
                              hipStream_t stream) {
    const float* gf    = (const float*)d_in[0];
    const int*   idx   = (const int*)  d_in[1];
    const float* W     = (const float*)d_in[3];
    const float* gamma = (const float*)d_in[4];
    const float* beta  = (const float*)d_in[5];
    const float* rmean = (const float*)d_in[6];
    const float* rvar  = (const float*)d_in[7];
    float*       out   = (float*)d_out;

    const int P  = in_sizes[0] / C_IN;
    const int M  = out_size / C_OUT;
    const int NB    = (M + BPILL - 1) >> BSHIFT;    // 1563 for M=200k
    const int NBpad = (NB + 32) & ~31;              // 1568
    const int E     = NREG * NBpad;                 // 12544 cells
    const int NSB   = (P + SCHUNK - 1) / SCHUNK;    // 489

    char* ws = (char*)d_ws;
    auto align256 = [](size_t x) { return (x + 255) & ~(size_t)255; };
    int* cnt = (int*)ws;  ws += align256((size_t)E * 4);
    int* ovf = (int*)ws;  ws += 256;
    char* arr = ws;                                 // payload planes OR tokens
    size_t fixed = (size_t)(arr - (char*)cnt);
    size_t avail = (ws_size > fixed) ? ws_size - fixed : 0;

    // mode select: payload scheme iff its ~72MB fits; else proven token scheme
    int CAPR;
    bool paym;
    if ((size_t)E * 240 * 24 <= avail) {            // cell mean ~160, max ~208
        paym = true;  CAPR = 240;
    } else {
        paym = false; CAPR = 512;
        while (CAPR > 128 && (size_t)E * CAPR * 4 > avail) CAPR -= 128;
    }
    const size_t PS = (size_t)E * CAPR;             // payload plane stride (u64)
    u64*      pay = (u64*)arr;
    unsigned* tok = (unsigned*)arr;

    hipMemsetAsync(cnt, 0, fixed, stream);          // cnt + ovf in one memset

    if (paym) {
        k_scatter<true ><<<NSB, SBLK, 0, stream>>>(idx, gf, W, gamma, beta,
            rmean, rvar, cnt, ovf, pay, tok, out, P, NBpad, CAPR, PS);
        k_pool  <true ><<<NB,  PBLK, 0, stream>>>(gf, pay, tok, cnt, ovf, W,
            gamma, beta, rmean, rvar, out, M, NBpad, CAPR, PS);
    } else {
        k_scatter<false><<<NSB, SBLK, 0, stream>>>(idx, gf, W, gamma, beta,
            rmean, rvar, cnt, ovf, pay, tok, out, P, NBpad, CAPR, PS);
        k_pool  <false><<<NB,  PBLK, 0, stream>>>(gf, pay, tok, cnt, ovf, W,
            gamma, beta, rmean, rvar, out, M, NBpad, CAPR, PS);
    }
}

// Round 6
// 256.714 us; speedup vs baseline: 1.1528x; 1.1528x over previous
//
#include <hip/hip_runtime.h>

// PillarMaxPooling: Linear(10->64,nobias) -> BN1d(eval,eps=1e-3) -> ReLU ->
// segment_max -> clamp0.
//
// R8 (262us): 4-kernel counting sort + pool(83us).
// R9/R10 (REVERTED): wider gather window / persistent blocks -> traffic up.
// R11 (216us): one-pass fixed-capacity (bucket,region) token scatter + pool.
//   Pool 82us: 2.1e8 B at 2.5TB/s random-granule = the bound.
// R12 (DIED): 77MB payload w/o ws_size check (OOB). ws>=72MB proven in R13.
// R13 (296us): SoA-plane payload: scatter WRITE 233MB (5x amp: 3 scattered
//   8B stores/point, 9MB/XCD window >> 4MB L2), occ 17% (489x256 grid), 135us.
// R14: fix the measured write-amp: (a) interleaved 24B records, cell base
//   64B-aligned -> 1 line/point not 3; (b) SBLK 1024 (PPT=4, same 489-block
//   grid -> ~7.8k waves ~95% occ) for RFO parallelism; (c) 4 sub-range store
//   passes (bucket windows, barriered) -> concurrent write window 2.2MB/XCD
//   < L2 -> partial lines merge before writeback. Pool: interleaved 3xu64
//   reads, otherwise R13 streaming structure. TOK fallback path kept.

#define C_IN   10
#define C_OUT  64
#define BSHIFT 7
#define BPILL  128
#define MAXNBP 2048              // supports M <= ~258k
#define NREG   8
#define SBLK   1024
#define SCHUNK 4096
#define PPT    (SCHUNK / SBLK)   // 4 points per thread
#define PBLK   512
#define TRASH  128               // acc row for masked lanes
#define SENT   (128u << 24)

typedef _Float16 half8 __attribute__((ext_vector_type(8)));
typedef float    f32x4 __attribute__((ext_vector_type(4)));
typedef unsigned long long u64;

// Overflow fallback: direct per-point MLP + device atomicMax on out.
// Never taken for the bench distribution; noinline keeps hot loop clean.
__device__ __attribute__((noinline))
void fallback_point(int p, int m, const float* gf, const float* W,
                    const float* gamma, const float* beta,
                    const float* rmean, const float* rvar,
                    float* out, int* ovf) {
    atomicExch(ovf, 1);
    const float* x = gf + (size_t)p * C_IN;
    unsigned* o = (unsigned*)out + (size_t)m * C_OUT;
#pragma clang loop unroll(disable)
    for (int c = 0; c < C_OUT; ++c) {
        float is = gamma[c] * rsqrtf(rvar[c] + 1e-3f);
        float bb = fmaf(-rmean[c], is, beta[c]);
        float d = 0.f;
        for (int k = 0; k < C_IN; ++k) d = fmaf(x[k], W[k * C_OUT + c], d);
        atomicMax(o + c, __float_as_uint(fmaxf(fmaf(d, is, bb), 0.f)));
    }
}

// ---------- K1: one-pass scatter into fixed-capacity (bucket,region) cells --
// phase1: LDS hist, per-point rank from atomic return (held in regs)
// phase2: one global atomicAdd per (block, nonempty bucket) -> cell base
// phase3: PAY: dense gf read + pkrtz + 24B record store, 4 bucket-window
//         passes (barriered) to keep the write frontier under L2;
//         TOK: 4B token store (single pass)
template <bool PAY>
__global__ __launch_bounds__(SBLK)
void k_scatter(const int* __restrict__ idx,
               const float* __restrict__ gf,
               const float* __restrict__ W,
               const float* __restrict__ gamma,
               const float* __restrict__ beta,
               const float* __restrict__ rmean,
               const float* __restrict__ rvar,
               int* __restrict__ cnt, int* __restrict__ ovf,
               u64* __restrict__ pay, unsigned* __restrict__ tok,
               float* __restrict__ out,
               int P, int NBpad, int CAPR) {
    __shared__ int lh[MAXNBP];
    __shared__ int rbase[MAXNBP];
    const int t = threadIdx.x;
    const int r = blockIdx.x & (NREG - 1);   // region ~ XCD (round-robin)

    for (int b = t; b < NBpad; b += SBLK) lh[b] = 0;
    __syncthreads();

    const int base = blockIdx.x * SCHUNK;
    int mm[PPT], rk[PPT];
#pragma unroll
    for (int i = 0; i < PPT; ++i) {
        int p = base + i * SBLK + t;
        mm[i] = (p < P) ? idx[p] : -1;
        rk[i] = (mm[i] >= 0) ? atomicAdd(&lh[mm[i] >> BSHIFT], 1) : 0;
    }
    __syncthreads();

    int* crow = cnt + (size_t)r * NBpad;
    for (int b = t; b < NBpad; b += SBLK) {
        int h = lh[b];
        rbase[b] = h ? atomicAdd(&crow[b], h) : 0;
    }
    __syncthreads();

    const float2* gf2 = (const float2*)gf;
    if constexpr (PAY) {
        const int NBQ = (NBpad + 3) >> 2;            // bucket window width
#pragma unroll
        for (int sp = 0; sp < 4; ++sp) {
            const int lo = sp * NBQ, hi = lo + NBQ;
#pragma unroll
            for (int i = 0; i < PPT; ++i) {
                if (mm[i] < 0) continue;
                int b = mm[i] >> BSHIFT;
                if (b < lo || b >= hi) continue;
                int p = base + i * SBLK + t;
                int slot = rbase[b] + rk[i];
                if (slot < CAPR) {
                    const float2* src = gf2 + (size_t)p * 5;   // dense 40B
                    float2 x0 = src[0], x1 = src[1], x2 = src[2];
                    float2 x3 = src[3], x4 = src[4];
                    unsigned u0 = __builtin_bit_cast(unsigned, __builtin_amdgcn_cvt_pkrtz(x0.x, x0.y));
                    unsigned u1 = __builtin_bit_cast(unsigned, __builtin_amdgcn_cvt_pkrtz(x1.x, x1.y));
                    unsigned u2 = __builtin_bit_cast(unsigned, __builtin_amdgcn_cvt_pkrtz(x2.x, x2.y));
                    unsigned u3 = __builtin_bit_cast(unsigned, __builtin_amdgcn_cvt_pkrtz(x3.x, x3.y));
                    unsigned u4 = __builtin_bit_cast(unsigned, __builtin_amdgcn_cvt_pkrtz(x4.x, x4.y));
                    u64* cp = pay + (((size_t)b * NREG + r) * CAPR + slot) * 3;
                    cp[0] = (u64)u0 | ((u64)u1 << 32);
                    cp[1] = (u64)u2 | ((u64)u3 << 32);
                    cp[2] = (u64)u4 |
                        ((u64)(unsigned)(mm[i] & (BPILL - 1)) << 32);
                } else {
                    fallback_point(p, mm[i], gf, W, gamma, beta, rmean, rvar,
                                   out, ovf);
                }
            }
            __syncthreads();                         // align write windows
        }
    } else {
#pragma unroll
        for (int i = 0; i < PPT; ++i) {
            if (mm[i] < 0) continue;
            int p = base + i * SBLK + t;
            int b = mm[i] >> BSHIFT;
            int slot = rbase[b] + rk[i];
            if (slot < CAPR) {
                tok[((size_t)b * NREG + r) * CAPR + slot] =
                    (unsigned)p | ((unsigned)(mm[i] & (BPILL - 1)) << 24);
            } else {
                fallback_point(p, mm[i], gf, W, gamma, beta, rmean, rvar,
                               out, ovf);
            }
        }
    }
}

// ---------- K2: pool — PAY: streaming 24B records; TOK: token + gf gather ---
template <bool PAY>
__global__ __launch_bounds__(PBLK, 8)
void k_pool(const float* __restrict__ gf,
            const u64* __restrict__ pay,
            const unsigned* __restrict__ tok,
            const int* __restrict__ cnt,
            const int* __restrict__ ovf,
            const float* __restrict__ W,
            const float* __restrict__ gamma,
            const float* __restrict__ beta,
            const float* __restrict__ rmean,
            const float* __restrict__ rvar,
            float* __restrict__ out, int M, int NBpad, int CAPR) {
    __shared__ unsigned int acc[129 * 65];   // stride 65; row 128 = trash
    const int t = threadIdx.x;
    const int lane = t & 63;
    const int wv = t >> 6;                   // wave == region 0..7
    const int n = lane & 15;
    const int q = lane >> 4;

    for (int i = t; i < 129 * 65; i += PBLK) acc[i] = 0u;

    // B fragments: W rows k>=10 zeroed -> A K-padding free
    half8 bfrag[4];
    float inv[4], bia[4];
#pragma unroll
    for (int tt = 0; tt < 4; ++tt) {
        int c = tt * 16 + n;
#pragma unroll
        for (int j = 0; j < 8; ++j) {
            int k = q * 8 + j;
            bfrag[tt][j] = (k < C_IN) ? (_Float16)W[k * C_OUT + c] : (_Float16)0.f;
        }
        float is = gamma[c] * rsqrtf(rvar[c] + 1e-3f);
        inv[tt] = is;
        bia[tt] = fmaf(-rmean[c], is, beta[c]);
    }
    __syncthreads();

    const int blk = blockIdx.x;
    const int cn = min(cnt[(size_t)wv * NBpad + blk], CAPR);   // real count
    const size_t cbase = ((size_t)blk * NREG + wv) * CAPR;
    const float2* gf2 = (const float2*)gf;

    for (int rb = 0; rb < cn; rb += 64) {
        int slot = rb + lane;
        int u0, u1, u2, u3, u4, ml;
        if constexpr (PAY) {
            // streaming: 3 u64 loads of a 24B record, linear wave-contiguous
            u64 w0 = 0, w1 = 0, w2 = ((u64)TRASH) << 32;
            if (slot < cn) {
                const u64* cp = pay + (cbase + slot) * 3;
                w0 = cp[0]; w1 = cp[1]; w2 = cp[2];
            }
            u0 = (int)(unsigned)w0; u1 = (int)(unsigned)(w0 >> 32);
            u2 = (int)(unsigned)w1; u3 = (int)(unsigned)(w1 >> 32);
            u4 = (int)(unsigned)w2; ml = (int)(unsigned)(w2 >> 32);
        } else {
            // token + random 40B gf gather (R11 path)
            unsigned v = (slot < cn) ? tok[cbase + slot] : SENT;
            const float2* src = gf2 + (size_t)(v & 0xFFFFFFu) * 5;
            float2 x0 = src[0], x1 = src[1], x2 = src[2];
            float2 x3 = src[3], x4 = src[4];
            u0 = __builtin_bit_cast(int, __builtin_amdgcn_cvt_pkrtz(x0.x, x0.y));
            u1 = __builtin_bit_cast(int, __builtin_amdgcn_cvt_pkrtz(x1.x, x1.y));
            u2 = __builtin_bit_cast(int, __builtin_amdgcn_cvt_pkrtz(x2.x, x2.y));
            u3 = __builtin_bit_cast(int, __builtin_amdgcn_cvt_pkrtz(x3.x, x3.y));
            u4 = __builtin_bit_cast(int, __builtin_amdgcn_cvt_pkrtz(x4.x, x4.y));
            ml = (int)(v >> 24);
        }

        const int ng = min(4, ((cn - rb) + 15) >> 4);   // 16-groups left
#pragma unroll
        for (int g = 0; g < 4; ++g) {
            if (g >= ng) break;              // wave-uniform
            const int sl = (g << 4) + n;     // source lane: point g*16+n
            int b0 = __shfl(u0, sl, 64);
            int b1 = __shfl(u1, sl, 64);
            int b2 = __shfl(u2, sl, 64);
            int b3 = __shfl(u3, sl, 64);
            int b4 = __shfl(u4, sl, 64);
            int4 a32;
            a32.x = (q == 0) ? b0 : ((q == 1) ? b4 : 0);
            a32.y = (q == 0) ? b1 : 0;
            a32.z = (q == 0) ? b2 : 0;
            a32.w = (q == 0) ? b3 : 0;
            half8 a = __builtin_bit_cast(half8, a32);
            f32x4 z = {0.f, 0.f, 0.f, 0.f};
            f32x4 d0 = __builtin_amdgcn_mfma_f32_16x16x32_f16(a, bfrag[0], z, 0, 0, 0);
            f32x4 d1 = __builtin_amdgcn_mfma_f32_16x16x32_f16(a, bfrag[1], z, 0, 0, 0);
            f32x4 d2 = __builtin_amdgcn_mfma_f32_16x16x32_f16(a, bfrag[2], z, 0, 0, 0);
            f32x4 d3 = __builtin_amdgcn_mfma_f32_16x16x32_f16(a, bfrag[3], z, 0, 0, 0);
#pragma unroll
            for (int r = 0; r < 4; ++r) {    // C row = 4q+r = point
                int mlr = __shfl(ml, (g << 4) + (q << 2) + r, 64);
                int abase = mlr * 65 + n;
                float h0 = fmaxf(fmaf(d0[r], inv[0], bia[0]), 0.f);
                float h1 = fmaxf(fmaf(d1[r], inv[1], bia[1]), 0.f);
                float h2 = fmaxf(fmaf(d2[r], inv[2], bia[2]), 0.f);
                float h3 = fmaxf(fmaf(d3[r], inv[3], bia[3]), 0.f);
                atomicMax(&acc[abase +  0], __float_as_uint(h0));
                atomicMax(&acc[abase + 16], __float_as_uint(h1));
                atomicMax(&acc[abase + 32], __float_as_uint(h2));
                atomicMax(&acc[abase + 48], __float_as_uint(h3));
            }
        }
    }
    __syncthreads();

    // coalesced writeback of 128 pillars x 64 channels; merge if overflow ran
    const int anyovf = ovf[0];
    const int mbase = blk * BPILL;
#pragma unroll
    for (int i = 0; i < (BPILL * C_OUT) / PBLK; ++i) {
        int wdx = i * PBLK + t;
        int row = wdx >> 6, c = wdx & 63;
        int m = mbase + row;
        if (m < M) {
            unsigned uv = acc[row * 65 + c];
            if (anyovf) atomicMax((unsigned*)out + (size_t)m * C_OUT + c, uv);
            else        out[(size_t)m * C_OUT + c] = __uint_as_float(uv);
        }
    }
}

extern "C" void kernel_launch(void* const* d_in, const int* in_sizes, int n_in,
                              void* d_out, int out_size, void* d_ws, size_t ws_size,
                              hipStream_t stream) {
    const float* gf    = (const float*)d_in[0];
    const int*   idx   = (const int*)  d_in[1];
    const float* W     = (const float*)d_in[3];
    const float* gamma = (const float*)d_in[4];
    const float* beta  = (const float*)d_in[5];
    const float* rmean = (const float*)d_in[6];
    const float* rvar  = (const float*)d_in[7];
    float*       out   = (float*)d_out;

    const int P  = in_sizes[0] / C_IN;
    const int M  = out_size / C_OUT;
    const int NB    = (M + BPILL - 1) >> BSHIFT;    // 1563 for M=200k
    const int NBpad = (NB + 32) & ~31;              // 1568
    const int E     = NREG * NBpad;                 // 12544 cells
    const int NSB   = (P + SCHUNK - 1) / SCHUNK;    // 489

    char* ws = (char*)d_ws;
    auto align256 = [](size_t x) { return (x + 255) & ~(size_t)255; };
    int* cnt = (int*)ws;  ws += align256((size_t)E * 4);
    int* ovf = (int*)ws;  ws += 256;
    char* arr = ws;                                 // payload records OR tokens
    size_t fixed = (size_t)(arr - (char*)cnt);
    size_t avail = (ws_size > fixed) ? ws_size - fixed : 0;

    // mode select: payload scheme iff its ~72MB fits; else proven token scheme
    int CAPR;
    bool paym;
    if ((size_t)E * 240 * 24 <= avail) {            // cell mean ~160, max ~215
        paym = true;  CAPR = 240;                   // 240*24=5760: 64B-aligned
    } else {
        paym = false; CAPR = 512;
        while (CAPR > 128 && (size_t)E * CAPR * 4 > avail) CAPR -= 128;
    }
    u64*      pay = (u64*)arr;
    unsigned* tok = (unsigned*)arr;

    hipMemsetAsync(cnt, 0, fixed, stream);          // cnt + ovf in one memset

    if (paym) {
        k_scatter<true ><<<NSB, SBLK, 0, stream>>>(idx, gf, W, gamma, beta,
            rmean, rvar, cnt, ovf, pay, tok, out, P, NBpad, CAPR);
        k_pool  <true ><<<NB,  PBLK, 0, stream>>>(gf, pay, tok, cnt, ovf, W,
            gamma, beta, rmean, rvar, out, M, NBpad, CAPR);
    } else {
        k_scatter<false><<<NSB, SBLK, 0, stream>>>(idx, gf, W, gamma, beta,
            rmean, rvar, cnt, ovf, pay, tok, out, P, NBpad, CAPR);
        k_pool  <false><<<NB,  PBLK, 0, stream>>>(gf, pay, tok, cnt, ovf, W,
            gamma, beta, rmean, rvar, out, M, NBpad, CAPR);
    }
}

// Round 7
// 211.110 us; speedup vs baseline: 1.4018x; 1.2160x over previous
//
#include <hip/hip_runtime.h>

// PillarMaxPooling: Linear(10->64,nobias) -> BN1d(eval,eps=1e-3) -> ReLU ->
// segment_max -> clamp0.
//
// R8 (262us): 4-kernel counting sort + pool(83us).
// R9/R10 (REVERTED): wider gather window / dynamic bucket order -> traffic up.
// R11 (216us): one-pass fixed-capacity (bucket,region) token scatter + pool.
//   Pool 82us: FETCH 155MB random 40B gather @2.5TB/s; Occupancy 66%.
// R12-R14 (DEAD END, measured): payload scatter moves MORE total bytes
//   (~250 vs ~220MB) + extra HBM round-trip; best PAY total 257 > 216.
// R15: back to R11 exactly, fix the measured occupancy tail. Pool occ 66% =
//   residency quantization: NB=1563 blocks / 1024 slots = 1.53 rounds (round
//   2 runs 539/1024 slots). Fix: bucket width 100 (not 128) -> NB=2000 =
//   1024+976 = 97.7% slot fill. idx/100 via compile-time magic-mul; acc
//   101x65 (26KB, still 4 blk/CU); cells mean 124, CAPR 256 (11 sigma).
//   Scatter: SBLK 1024 / SCHUNK 4096 -> 489 blocks ~95% of 512 slots, 2x
//   waves for store/atomic latency. Everything else byte-identical to R11.

#define C_IN   10
#define C_OUT  64
#define BPILL  100               // bucket width in pillars (not pow2; magic-mul)
#define MAXNBP 2048              // bucket arrays; supports M <= ~201k
#define NREG   8
#define SBLK   1024
#define SCHUNK 4096
#define PPT    (SCHUNK / SBLK)   // 4 points per thread
#define PBLK   512
#define TRASH  100               // acc row for masked lanes
#define SENT   ((unsigned)TRASH << 24)

typedef _Float16 half8 __attribute__((ext_vector_type(8)));
typedef float    f32x4 __attribute__((ext_vector_type(4)));

// Overflow fallback: direct per-point MLP + device atomicMax on out.
// Never taken for the bench distribution (11-sigma margin); noinline keeps
// the hot scatter loop's register budget clean.
__device__ __attribute__((noinline))
void fallback_point(int p, int m, const float* gf, const float* W,
                    const float* gamma, const float* beta,
                    const float* rmean, const float* rvar,
                    float* out, int* ovf) {
    atomicExch(ovf, 1);
    const float* x = gf + (size_t)p * C_IN;
    unsigned* o = (unsigned*)out + (size_t)m * C_OUT;
#pragma clang loop unroll(disable)
    for (int c = 0; c < C_OUT; ++c) {
        float is = gamma[c] * rsqrtf(rvar[c] + 1e-3f);
        float bb = fmaf(-rmean[c], is, beta[c]);
        float d = 0.f;
        for (int k = 0; k < C_IN; ++k) d = fmaf(x[k], W[k * C_OUT + c], d);
        atomicMax(o + c, __float_as_uint(fmaxf(fmaf(d, is, bb), 0.f)));
    }
}

// ---------- K1: one-pass token scatter into (bucket,region) cells ----------
// phase1: LDS hist, per-point rank from atomic return (held in regs)
// phase2: one global atomicAdd per (block, nonempty bucket) -> cell base
// phase3: scatter 4B tokens to tok[(b*NREG+r)*CAPR + slot]
__global__ __launch_bounds__(SBLK)
void k_scatter(const int* __restrict__ idx,
               const float* __restrict__ gf,
               const float* __restrict__ W,
               const float* __restrict__ gamma,
               const float* __restrict__ beta,
               const float* __restrict__ rmean,
               const float* __restrict__ rvar,
               int* __restrict__ cnt, int* __restrict__ ovf,
               unsigned* __restrict__ tok,
               float* __restrict__ out,
               int P, int NBpad, int CAPR) {
    __shared__ int lh[MAXNBP];
    __shared__ int rbase[MAXNBP];
    const int t = threadIdx.x;
    const int r = blockIdx.x & (NREG - 1);   // region ~ XCD (round-robin)

    for (int b = t; b < NBpad; b += SBLK) lh[b] = 0;
    __syncthreads();

    const int base = blockIdx.x * SCHUNK;
    int mm[PPT], rk[PPT];
#pragma unroll
    for (int i = 0; i < PPT; ++i) {
        int p = base + i * SBLK + t;
        mm[i] = (p < P) ? idx[p] : -1;
        rk[i] = (mm[i] >= 0) ? atomicAdd(&lh[mm[i] / BPILL], 1) : 0;
    }
    __syncthreads();

    int* crow = cnt + (size_t)r * NBpad;
    for (int b = t; b < NBpad; b += SBLK) {
        int h = lh[b];
        rbase[b] = h ? atomicAdd(&crow[b], h) : 0;
    }
    __syncthreads();

#pragma unroll
    for (int i = 0; i < PPT; ++i) {
        if (mm[i] < 0) continue;
        int p = base + i * SBLK + t;
        int b = mm[i] / BPILL;
        int ml = mm[i] - b * BPILL;          // idx % 100
        int slot = rbase[b] + rk[i];
        if (slot < CAPR) {
            tok[((size_t)b * NREG + r) * CAPR + slot] =
                (unsigned)p | ((unsigned)ml << 24);
        } else {
            fallback_point(p, mm[i], gf, W, gamma, beta, rmean, rvar, out, ovf);
        }
    }
}

// ---------- K2: pool — static grid, 64-token lane-per-point gather, MFMA ----
__global__ __launch_bounds__(PBLK, 8)
void k_pool(const float* __restrict__ gf,
            const unsigned* __restrict__ tok,
            const int* __restrict__ cnt,
            const int* __restrict__ ovf,
            const float* __restrict__ W,
            const float* __restrict__ gamma,
            const float* __restrict__ beta,
            const float* __restrict__ rmean,
            const float* __restrict__ rvar,
            float* __restrict__ out, int M, int NBpad, int CAPR) {
    __shared__ unsigned int acc[(BPILL + 1) * 65];  // stride 65; row 100 = trash
    const int t = threadIdx.x;
    const int lane = t & 63;
    const int wv = t >> 6;                   // wave == region 0..7
    const int n = lane & 15;
    const int q = lane >> 4;

    for (int i = t; i < (BPILL + 1) * 65; i += PBLK) acc[i] = 0u;

    // B fragments: W rows k>=10 zeroed -> A K-padding free
    half8 bfrag[4];
    float inv[4], bia[4];
#pragma unroll
    for (int tt = 0; tt < 4; ++tt) {
        int c = tt * 16 + n;
#pragma unroll
        for (int j = 0; j < 8; ++j) {
            int k = q * 8 + j;
            bfrag[tt][j] = (k < C_IN) ? (_Float16)W[k * C_OUT + c] : (_Float16)0.f;
        }
        float is = gamma[c] * rsqrtf(rvar[c] + 1e-3f);
        inv[tt] = is;
        bia[tt] = fmaf(-rmean[c], is, beta[c]);
    }
    __syncthreads();

    const int blk = blockIdx.x;
    const int cn = min(cnt[(size_t)wv * NBpad + blk], CAPR);   // real count
    const unsigned* src0 = tok + ((size_t)blk * NREG + wv) * CAPR;
    const float2* gf2 = (const float2*)gf;

    for (int rb = 0; rb < cn; rb += 64) {
        // lane-per-point: full-wave 40B contiguous gather + packed cvt
        unsigned v = (rb + lane < cn) ? src0[rb + lane] : SENT;
        const float2* src = gf2 + (size_t)(v & 0xFFFFFFu) * 5;
        float2 x0 = src[0], x1 = src[1], x2 = src[2], x3 = src[3], x4 = src[4];
        int u0 = __builtin_bit_cast(int, __builtin_amdgcn_cvt_pkrtz(x0.x, x0.y));
        int u1 = __builtin_bit_cast(int, __builtin_amdgcn_cvt_pkrtz(x1.x, x1.y));
        int u2 = __builtin_bit_cast(int, __builtin_amdgcn_cvt_pkrtz(x2.x, x2.y));
        int u3 = __builtin_bit_cast(int, __builtin_amdgcn_cvt_pkrtz(x3.x, x3.y));
        int u4 = __builtin_bit_cast(int, __builtin_amdgcn_cvt_pkrtz(x4.x, x4.y));

        const int ng = min(4, ((cn - rb) + 15) >> 4);   // 16-groups left
#pragma unroll
        for (int g = 0; g < 4; ++g) {
            if (g >= ng) break;              // wave-uniform
            const int sl = (g << 4) + n;     // source lane: point g*16+n
            int b0 = __shfl(u0, sl, 64);
            int b1 = __shfl(u1, sl, 64);
            int b2 = __shfl(u2, sl, 64);
            int b3 = __shfl(u3, sl, 64);
            int b4 = __shfl(u4, sl, 64);
            int4 a32;
            a32.x = (q == 0) ? b0 : ((q == 1) ? b4 : 0);
            a32.y = (q == 0) ? b1 : 0;
            a32.z = (q == 0) ? b2 : 0;
            a32.w = (q == 0) ? b3 : 0;
            half8 a = __builtin_bit_cast(half8, a32);
            f32x4 z = {0.f, 0.f, 0.f, 0.f};
            f32x4 d0 = __builtin_amdgcn_mfma_f32_16x16x32_f16(a, bfrag[0], z, 0, 0, 0);
            f32x4 d1 = __builtin_amdgcn_mfma_f32_16x16x32_f16(a, bfrag[1], z, 0, 0, 0);
            f32x4 d2 = __builtin_amdgcn_mfma_f32_16x16x32_f16(a, bfrag[2], z, 0, 0, 0);
            f32x4 d3 = __builtin_amdgcn_mfma_f32_16x16x32_f16(a, bfrag[3], z, 0, 0, 0);
#pragma unroll
            for (int r = 0; r < 4; ++r) {    // C row = 4q+r = point
                int mlr = __shfl((int)v, (g << 4) + (q << 2) + r, 64);
                int abase = (int)(((unsigned)mlr) >> 24) * 65 + n;   // ml row
                float h0 = fmaxf(fmaf(d0[r], inv[0], bia[0]), 0.f);
                float h1 = fmaxf(fmaf(d1[r], inv[1], bia[1]), 0.f);
                float h2 = fmaxf(fmaf(d2[r], inv[2], bia[2]), 0.f);
                float h3 = fmaxf(fmaf(d3[r], inv[3], bia[3]), 0.f);
                atomicMax(&acc[abase +  0], __float_as_uint(h0));
                atomicMax(&acc[abase + 16], __float_as_uint(h1));
                atomicMax(&acc[abase + 32], __float_as_uint(h2));
                atomicMax(&acc[abase + 48], __float_as_uint(h3));
            }
        }
    }
    __syncthreads();

    // coalesced writeback of 100 pillars x 64 channels; merge if overflow ran
    const int anyovf = ovf[0];
    const int mbase = blk * BPILL;
#pragma unroll
    for (int i = 0; i < (BPILL * C_OUT + PBLK - 1) / PBLK; ++i) {
        int wdx = i * PBLK + t;
        if (wdx >= BPILL * C_OUT) break;
        int row = wdx >> 6, c = wdx & 63;
        int m = mbase + row;
        if (m < M) {
            unsigned uv = acc[row * 65 + c];
            if (anyovf) atomicMax((unsigned*)out + (size_t)m * C_OUT + c, uv);
            else        out[(size_t)m * C_OUT + c] = __uint_as_float(uv);
        }
    }
}

extern "C" void kernel_launch(void* const* d_in, const int* in_sizes, int n_in,
                              void* d_out, int out_size, void* d_ws, size_t ws_size,
                              hipStream_t stream) {
    const float* gf    = (const float*)d_in[0];
    const int*   idx   = (const int*)  d_in[1];
    const float* W     = (const float*)d_in[3];
    const float* gamma = (const float*)d_in[4];
    const float* beta  = (const float*)d_in[5];
    const float* rmean = (const float*)d_in[6];
    const float* rvar  = (const float*)d_in[7];
    float*       out   = (float*)d_out;

    const int P  = in_sizes[0] / C_IN;
    const int M  = out_size / C_OUT;
    const int NB    = (M + BPILL - 1) / BPILL;      // 2000 for M=200k
    const int NBpad = (NB + 32) & ~31;              // 2016 (<= MAXNBP)
    const int E     = NREG * NBpad;                 // 16128 cells
    const int NSB   = (P + SCHUNK - 1) / SCHUNK;    // 489

    char* ws = (char*)d_ws;
    auto align256 = [](size_t x) { return (x + 255) & ~(size_t)255; };
    int* cnt = (int*)ws;  ws += align256((size_t)E * 4);
    int* ovf = (int*)ws;  ws += 256;
    unsigned* tok = (unsigned*)ws;

    // capacity per (bucket,region) cell; shrink if workspace is small
    int CAPR = 256;                                  // cell mean ~124, max ~175
    size_t fixed = (size_t)((char*)tok - (char*)cnt);
    size_t avail = (ws_size > fixed) ? ws_size - fixed : 0;
    while (CAPR > 128 && (size_t)E * CAPR * 4 > avail) CAPR -= 64;

    hipMemsetAsync(cnt, 0, fixed, stream);           // cnt + ovf in one memset

    k_scatter<<<NSB, SBLK, 0, stream>>>(idx, gf, W, gamma, beta, rmean, rvar,
                                        cnt, ovf, tok, out, P, NBpad, CAPR);
    k_pool   <<<NB,  PBLK, 0, stream>>>(gf, tok, cnt, ovf, W, gamma, beta,
                                        rmean, rvar, out, M, NBpad, CAPR);
}